// Round 10
// baseline (24.733 us; speedup 1.0000x reference)
//
#include <hip/hip_runtime.h>
#include <math.h>

// VoronoiDecoder: N=65536 x S=32. 16 lanes/point (one DPP row), 2 seeds/lane.
// All cross-lane exchange via DPP row_ror (VALU pipe) -- ZERO DS in the pair
// phase, no LDS slabs, no table. 33 pair-evals/thread (1 in-lane + 8 ring
// rotations x 4; r=8 half-weight). Sigmoid split 50/50 between Pade[7/6]
// (VALU) and exp2+rcp (trans) to balance the two per-SIMD pipes.
// LDS: only the 32 seed metrics (~900B). No launch_bounds reg pin.

#define LOG2E 1.4426950408889634f
#define EPSF  1e-8f
#define BLOCK 256
#define PPBLK (BLOCK / 16)      // 16 points per block

// rotate by 1 within each 16-lane row (wrap); row_ror:1 = 0x121
#define ROR1(X) __int_as_float(__builtin_amdgcn_mov_dpp(                   \
                    __float_as_int(X), 0x121, 0xf, 0xf, false))
// full 16-lane row reduction (all lanes end with the row total)
#define RSUM16(X)                                                          \
    {                                                                      \
        (X) += __int_as_float(__builtin_amdgcn_mov_dpp(                    \
                   __float_as_int(X), 0x128, 0xf, 0xf, false));            \
        (X) += __int_as_float(__builtin_amdgcn_mov_dpp(                    \
                   __float_as_int(X), 0x124, 0xf, 0xf, false));            \
        (X) += __int_as_float(__builtin_amdgcn_mov_dpp(                    \
                   __float_as_int(X), 0x122, 0xf, 0xf, false));            \
        (X) += __int_as_float(__builtin_amdgcn_mov_dpp(                    \
                   __float_as_int(X), 0x121, 0xf, 0xf, false));            \
    }

__global__ __launch_bounds__(BLOCK) void voronoi_v10(
    const float* __restrict__ points,   // (N,2)
    const float* __restrict__ seeds,    // (32,2)
    const float* __restrict__ w_raw,    // (1,)
    const float* __restrict__ theta,    // (32,)
    const float* __restrict__ a_raw,    // (32,)
    float* __restrict__ out,            // (N,)
    int N)
{
    __shared__ float s_su[32], s_sv[32], s_m00[32], s_m01[32], s_m11[32];

    const int t = threadIdx.x;

    // uniform band half-width
    const float wr = w_raw[0];
    const float sg = __builtin_amdgcn_rcpf(1.0f + exp2f(wr * (-LOG2E / 5.0f)));
    const float w  = 0.005f + 0.495f * sg;
    const float wc25 = 25.0f * w;                  // w/(2*beta)
    const float C1 = 50.0f * LOG2E;                // 1/beta * log2(e)
    const float C0 = -w * C1;

    // seed metrics (natural units; 2x folded into m01)
    if (t < 32) {
        const float x  = a_raw[t];
        const float z  = exp2f(2.0f * LOG2E * x);
        const float th = (z - 1.0f) * __builtin_amdgcn_rcpf(z + 1.0f);  // tanh
        const float a  = 0.75f * th + 1.25f;
        const float ia = __builtin_amdgcn_rcpf(a + EPSF);
        const float cs = __cosf(theta[t]);
        const float sn = __sinf(theta[t]);
        s_m00[t] = a * cs * cs + ia * sn * sn;
        s_m01[t] = 2.0f * cs * sn * (ia - a);
        s_m11[t] = a * sn * sn + ia * cs * cs;
        s_su[t]  = seeds[2 * t];
        s_sv[t]  = seeds[2 * t + 1];
    }
    __syncthreads();   // only barrier

    const int l = t & 15;                       // lane within the point row
    const int p = blockIdx.x * PPBLK + (t >> 4);
    if (p >= N) return;

    const int s0 = l * 2;                       // this lane's 2 seeds
    const float2 su = *(const float2*)&s_su[s0];
    const float2 sv = *(const float2*)&s_sv[s0];
    const float2 m0 = *(const float2*)&s_m00[s0];
    const float2 m1 = *(const float2*)&s_m01[s0];
    const float2 m2 = *(const float2*)&s_m11[s0];

    const float2 uv = ((const float2*)points)[p];
    const float u = uv.x, v = uv.y;

    float d0, d1;
#define DIST(SU, SV, M00, M01, M11, OUTD)                                  \
    {                                                                      \
        float du = u - (SU); du -= rintf(du);                              \
        float dv = v - (SV); dv -= rintf(dv);                              \
        float q = fmaf(du * du, (M00),                                     \
                  fmaf(du * dv, (M01),                                     \
                  fmaf(dv * dv, (M11), EPSF)));                            \
        (OUTD) = sqrtf(q);                                                 \
    }
    DIST(su.x, sv.x, m0.x, m1.x, m2.x, d0)
    DIST(su.y, sv.y, m0.y, m1.y, m2.y, d1)

    // softmax over 32 seeds (16 lanes x 2); exponents >= -29, no max-sub
    const float cE = -20.0f * LOG2E;
    const float e0 = exp2f(d0 * cE);
    const float e1 = exp2f(d1 * cE);
    float Z = e0 + e1;
    RSUM16(Z)
    const float rcpZ = __builtin_amdgcn_rcpf(Z);
    const float w0 = e0 * rcpZ;
    const float w1 = e1 * rcpZ;
    float sumsq = fmaf(w0, w0, w1 * w1);

    // ---- pair evals ----
    // Pade[7/6] tanh on VALU: B = 0.5 + 0.5*tanh(x), x = (w-|D|)/(2*beta)
#define PBODY(DI, DJ, WJ, ACC)                                             \
    {                                                                      \
        float x = fmaf(fabsf((DI) - (DJ)), -25.0f, wc25);                  \
        x = fminf(fmaxf(x, -4.6f), 4.6f);                                  \
        const float tt = x * x;                                            \
        const float nm = fmaf(fmaf(tt + 378.0f, tt, 17325.0f), tt,         \
                              135135.0f);                                  \
        const float dn = fmaf(fmaf(fmaf(28.0f, tt, 3150.0f), tt,           \
                              62370.0f), tt, 135135.0f);                   \
        const float B  = fmaf(x * __builtin_amdgcn_rcpf(dn) * nm,          \
                              0.5f, 0.5f);                                 \
        (ACC) = fmaf((WJ), B, (ACC));                                      \
    }
    // exp2+rcp sigmoid on trans pipe
#define EBODY(DI, DJ, WJ, ACC)                                             \
    {                                                                      \
        const float yy = exp2f(fmaf(fabsf((DI) - (DJ)), C1, C0));          \
        (ACC) = fmaf((WJ), __builtin_amdgcn_rcpf(1.0f + yy), (ACC));       \
    }

    float acc0 = 0.0f, acc1 = 0.0f;
    EBODY(d0, d1, w1, acc0)          // in-lane pair (seed 2l, 2l+1)

    float rd0 = d0, rd1 = d1, rw0 = w0, rw1 = w1;
#define STEP(HALF)                                                         \
    {                                                                      \
        rd0 = ROR1(rd0); rd1 = ROR1(rd1);                                  \
        rw0 = ROR1(rw0); rw1 = ROR1(rw1);                                  \
        float uw0 = rw0, uw1 = rw1;                                        \
        if (HALF) { uw0 *= 0.5f; uw1 *= 0.5f; }                            \
        PBODY(d0, rd0, uw0, acc0)                                          \
        EBODY(d0, rd1, uw1, acc0)                                          \
        EBODY(d1, rd0, uw0, acc1)                                          \
        PBODY(d1, rd1, uw1, acc1)                                          \
    }
    STEP(0) STEP(0) STEP(0) STEP(0)
    STEP(0) STEP(0) STEP(0)
    STEP(1)                           // r=8: each pair seen twice -> half

    // numerator and pair-mass reductions over the 16-lane row
    float nb = fmaf(w0, acc0, w1 * acc1);
    RSUM16(nb)
    RSUM16(sumsq)

    // pair mass: sum_{i<j} w_i w_j = (1 - sum w^2)/2
    const float den   = fmaxf(0.5f * (1.0f - sumsq), 0.0f) + EPSF;
    const float ratio = nb * __builtin_amdgcn_rcpf(den);
    const float rho   = 1.0f - exp2f(ratio * (-8.0f * LOG2E));
    if (l == 0) out[p] = rho;
}

extern "C" void kernel_launch(void* const* d_in, const int* in_sizes, int n_in,
                              void* d_out, int out_size, void* d_ws, size_t ws_size,
                              hipStream_t stream) {
    const float* points = (const float*)d_in[0];
    const float* seeds  = (const float*)d_in[1];
    const float* w_raw  = (const float*)d_in[2];
    const float* theta  = (const float*)d_in[3];
    const float* a_raw  = (const float*)d_in[4];
    float* out = (float*)d_out;

    const int N = in_sizes[0] / 2;                  // 65536
    const int grid = (N + PPBLK - 1) / PPBLK;       // 4096 blocks

    voronoi_v10<<<grid, BLOCK, 0, stream>>>(points, seeds, w_raw, theta, a_raw,
                                            out, N);
}

// Round 11
// 15.663 us; speedup vs baseline: 1.5790x; 1.5790x over previous
//
#include <hip/hip_runtime.h>
#include <math.h>

// VoronoiDecoder: N=65536 x S=32. 8 lanes/point, 4 seeds/lane, 512-thr blocks,
// 64 points/block, grid=1024 (4 blocks/CU exact). All pair-sigmoids via full-
// range LDS table (pre-shifted byte indices; body = max,min,sub,ds_read,fma).
// R11 cuts vs R7: ROT(4) diag/anti-diag split (-8 reads, -24 VALU, exact
// coverage), quad_perm DPP for xor1/xor2 reduction stages (9 -> 3 DS
// shuffles), no clamps (-2 VALU/pair). launch_bounds(512,8) proven in R7.

#define LOG2E 1.4426950408889634f
#define EPSF  1e-8f
#define TSC   4096.0f           // distance quant units per 1.0
#define TAB_N 4160              // full range: idx diff <= 4096
#define BLOCK 512
#define PPB   64                // points per block
#define SSTR  40                // slab row stride (words): 2-way banks = free

// in-place add of quad_perm-permuted value (exact xor1/xor2 within quads)
#define DPP_ADD(X, CTRL)                                                   \
    (X) += __int_as_float(__builtin_amdgcn_mov_dpp(                        \
               __float_as_int(X), (CTRL), 0xf, 0xf, false));

__global__ __launch_bounds__(BLOCK, 8) void voronoi_v11(
    const float* __restrict__ points,   // (N,2)
    const float* __restrict__ seeds,    // (32,2)
    const float* __restrict__ w_raw,    // (1,)
    const float* __restrict__ theta,    // (32,)
    const float* __restrict__ a_raw,    // (32,)
    float* __restrict__ out,            // (N,)
    int N)
{
    __shared__ float    s_tab[TAB_N];
    __shared__ unsigned s_ii[PPB * SSTR];
    __shared__ float    s_ww[PPB * SSTR];
    __shared__ float    s_su[32], s_sv[32], s_m00[32], s_m01[32], s_m11[32];

    const int t = threadIdx.x;

    // uniform band half-width
    const float wr = w_raw[0];
    const float sg = __builtin_amdgcn_rcpf(1.0f + exp2f(wr * (-LOG2E / 5.0f)));
    const float w  = 0.005f + 0.495f * sg;

    // seed metrics, pre-scaled so sqrt lands in table units (2x folded in m01)
    if (t < 32) {
        const float x  = a_raw[t];
        const float z  = exp2f(2.0f * LOG2E * x);
        const float th = (z - 1.0f) * __builtin_amdgcn_rcpf(z + 1.0f);  // tanh
        const float a  = 0.75f * th + 1.25f;
        const float ia = __builtin_amdgcn_rcpf(a + EPSF);
        const float cs = __cosf(theta[t]);
        const float sn = __sinf(theta[t]);
        const float S2 = TSC * TSC;
        s_m00[t] = (a * cs * cs + ia * sn * sn) * S2;
        s_m01[t] = (2.0f * cs * sn * (ia - a)) * S2;
        s_m11[t] = (a * sn * sn + ia * cs * cs) * S2;
        s_su[t]  = seeds[2 * t];
        s_sv[t]  = seeds[2 * t + 1];
    }
    // full band table: T[k] = sigmoid((w - k/TSC)/0.02)
    {
        const float kC = (50.0f * LOG2E) / TSC;
        const float kB = -w * (50.0f * LOG2E);
        for (int k = t; k < TAB_N; k += BLOCK) {
            const float y = exp2f(fmaf((float)k, kC, kB));
            s_tab[k] = __builtin_amdgcn_rcpf(1.0f + y);
        }
    }
    __syncthreads();   // only barrier; slab exchange below is same-wave

    const int pb = t >> 3;              // point slot (0..63)
    const int g  = t & 7;               // seed group
    const int s0 = g * 4;
    const int p  = blockIdx.x * PPB + pb;
    if (p >= N) return;

    const float4 su4  = *(const float4*)&s_su[s0];
    const float4 sv4  = *(const float4*)&s_sv[s0];
    const float4 m004 = *(const float4*)&s_m00[s0];
    const float4 m014 = *(const float4*)&s_m01[s0];
    const float4 m114 = *(const float4*)&s_m11[s0];

    const float2 uv = ((const float2*)points)[p];
    const float u = uv.x, v = uv.y;

    const float EPS_Q = 1e-8f * TSC * TSC;
    float4 d4;
#define DIST(SU, SV, M00, M01, M11, OUTD)                                  \
    {                                                                      \
        float du = u - (SU); du -= rintf(du);                              \
        float dv = v - (SV); dv -= rintf(dv);                              \
        float q = fmaf(du * du, (M00),                                     \
                  fmaf(du * dv, (M01),                                     \
                  fmaf(dv * dv, (M11), EPS_Q)));                           \
        (OUTD) = sqrtf(q);                                                 \
    }
    DIST(su4.x, sv4.x, m004.x, m014.x, m114.x, d4.x)
    DIST(su4.y, sv4.y, m004.y, m014.y, m114.y, d4.y)
    DIST(su4.z, sv4.z, m004.z, m014.z, m114.z, d4.z)
    DIST(su4.w, sv4.w, m004.w, m014.w, m114.w, d4.w)

    // softmax over 32 seeds (exponents bounded below ~ -29; no max-sub)
    const float cE = -(20.0f * LOG2E) / TSC;
    float4 e4;
    e4.x = exp2f(d4.x * cE);
    e4.y = exp2f(d4.y * cE);
    e4.z = exp2f(d4.z * cE);
    e4.w = exp2f(d4.w * cE);
    float Z = (e4.x + e4.y) + (e4.z + e4.w);
    DPP_ADD(Z, 0xB1)                    // + lane^1 (quad_perm 1,0,3,2)
    DPP_ADD(Z, 0x4E)                    // + lane^2 (quad_perm 2,3,0,1)
    Z += __shfl_xor(Z, 4, 64);          // + lane^4
    const float rcpZ = __builtin_amdgcn_rcpf(Z);
    float4 w4;
    w4.x = e4.x * rcpZ; w4.y = e4.y * rcpZ;
    w4.z = e4.z * rcpZ; w4.w = e4.w * rcpZ;
    float sq = w4.x * w4.x;
    sq = fmaf(w4.y, w4.y, sq);
    sq = fmaf(w4.z, w4.z, sq);
    sq = fmaf(w4.w, w4.w, sq);

    // quantize to pre-shifted byte offsets
    uint4 ii;
    ii.x = ((unsigned)(d4.x + 0.5f)) << 2;
    ii.y = ((unsigned)(d4.y + 0.5f)) << 2;
    ii.z = ((unsigned)(d4.z + 0.5f)) << 2;
    ii.w = ((unsigned)(d4.w + 0.5f)) << 2;

    // stage to this point's slab row (same-wave exchange, no barrier)
    unsigned* db = &s_ii[pb * SSTR];
    float*    wb = &s_ww[pb * SSTR];
    *(uint4*) (db + s0) = ii;
    *(float4*)(wb + s0) = w4;

    const char* tb = (const char*)s_tab;

#define TBODY(IA, IB, WJ, ACC)                                             \
    {                                                                      \
        const unsigned hi = (IA) > (IB) ? (IA) : (IB);                     \
        const unsigned lo = (IA) > (IB) ? (IB) : (IA);                     \
        const float B = *(const float*)(tb + (hi - lo));                   \
        (ACC) = fmaf((WJ), B, (ACC));                                      \
    }

    // 6 in-lane pairs
    float b0, b1, b2, b3;
    b0 = 0.0f; b1 = 0.0f; b2 = 0.0f; b3 = 0.0f;
    TBODY(ii.x, ii.y, w4.y, b0)
    TBODY(ii.x, ii.z, w4.z, b0)
    TBODY(ii.x, ii.w, w4.w, b0)
    TBODY(ii.y, ii.z, w4.z, b1)
    TBODY(ii.y, ii.w, w4.w, b1)
    TBODY(ii.z, ii.w, w4.w, b2)

#define ROT(R)                                                             \
    {                                                                      \
        const int gj = ((g + (R)) & 7) * 4;                                \
        const uint4  ij = *(const uint4*) (db + gj);                       \
        const float4 wj = *(const float4*)(wb + gj);                       \
        TBODY(ii.x, ij.x, wj.x, b0)                                        \
        TBODY(ii.x, ij.y, wj.y, b0)                                        \
        TBODY(ii.x, ij.z, wj.z, b0)                                        \
        TBODY(ii.x, ij.w, wj.w, b0)                                        \
        TBODY(ii.y, ij.x, wj.x, b1)                                        \
        TBODY(ii.y, ij.y, wj.y, b1)                                        \
        TBODY(ii.y, ij.z, wj.z, b1)                                        \
        TBODY(ii.y, ij.w, wj.w, b1)                                        \
        TBODY(ii.z, ij.x, wj.x, b2)                                        \
        TBODY(ii.z, ij.y, wj.y, b2)                                        \
        TBODY(ii.z, ij.z, wj.z, b2)                                        \
        TBODY(ii.z, ij.w, wj.w, b2)                                        \
        TBODY(ii.w, ij.x, wj.x, b3)                                        \
        TBODY(ii.w, ij.y, wj.y, b3)                                        \
        TBODY(ii.w, ij.z, wj.z, b3)                                        \
        TBODY(ii.w, ij.w, wj.w, b3)                                        \
    }
    ROT(1)
    ROT(2)
    ROT(3)

    // ROT(4): pair (g, g+4) seen from both lanes -> split the 4x4 combo grid:
    // lanes g<4 do the diagonal 2x2 blocks, lanes g>=4 the anti-diagonal ones.
    // Exact single coverage of all 16 combos, full weight, 8 reads per lane.
    {
        const int gj = ((g + 4) & 7) * 4;
        const uint4  ij = *(const uint4*) (db + gj);
        const float4 wj = *(const float4*)(wb + gj);
        const bool lo4 = (g < 4);
        const unsigned cA0 = lo4 ? ij.x : ij.z;
        const unsigned cA1 = lo4 ? ij.y : ij.w;
        const float    vA0 = lo4 ? wj.x : wj.z;
        const float    vA1 = lo4 ? wj.y : wj.w;
        const unsigned cB0 = lo4 ? ij.z : ij.x;
        const unsigned cB1 = lo4 ? ij.w : ij.y;
        const float    vB0 = lo4 ? wj.z : wj.x;
        const float    vB1 = lo4 ? wj.w : wj.y;
        TBODY(ii.x, cA0, vA0, b0)
        TBODY(ii.x, cA1, vA1, b0)
        TBODY(ii.y, cA0, vA0, b1)
        TBODY(ii.y, cA1, vA1, b1)
        TBODY(ii.z, cB0, vB0, b2)
        TBODY(ii.z, cB1, vB1, b2)
        TBODY(ii.w, cB0, vB0, b3)
        TBODY(ii.w, cB1, vB1, b3)
    }

    float nb = w4.x * b0;
    nb = fmaf(w4.y, b1, nb);
    nb = fmaf(w4.z, b2, nb);
    nb = fmaf(w4.w, b3, nb);

    // reduce over the point's 8 lanes (xor1/xor2 on DPP, xor4 via swizzle)
    DPP_ADD(nb, 0xB1)
    DPP_ADD(sq, 0xB1)
    DPP_ADD(nb, 0x4E)
    DPP_ADD(sq, 0x4E)
    nb += __shfl_xor(nb, 4, 64);
    sq += __shfl_xor(sq, 4, 64);

    // pair mass: sum_{i<j} w_i w_j = (1 - sum w^2)/2
    const float den   = fmaxf(0.5f * (1.0f - sq), 0.0f) + EPSF;
    const float ratio = nb * __builtin_amdgcn_rcpf(den);
    const float rho   = 1.0f - exp2f(ratio * (-8.0f * LOG2E));
    if (g == 0) out[p] = rho;
}

extern "C" void kernel_launch(void* const* d_in, const int* in_sizes, int n_in,
                              void* d_out, int out_size, void* d_ws, size_t ws_size,
                              hipStream_t stream) {
    const float* points = (const float*)d_in[0];
    const float* seeds  = (const float*)d_in[1];
    const float* w_raw  = (const float*)d_in[2];
    const float* theta  = (const float*)d_in[3];
    const float* a_raw  = (const float*)d_in[4];
    float* out = (float*)d_out;

    const int N = in_sizes[0] / 2;              // 65536
    const int grid = (N + PPB - 1) / PPB;       // 1024 blocks, 4/CU exact

    voronoi_v11<<<grid, BLOCK, 0, stream>>>(points, seeds, w_raw, theta, a_raw,
                                            out, N);
}